// Round 6
// baseline (717.758 us; speedup 1.0000x reference)
//
#include <hip/hip_runtime.h>

// RGAT encoder, 2 layers. N=32768, E=160000, DIM=768, R=3, heads 4 then 1.
// Round 10 (from 662 us): R9's swizzle change moved conflicts by ZERO
// (1.062e7 = exactly 4 cyc x 2.65M ds_read_b128 in both R8/R9) -> per-lane
// remap can't fix it; the row-PAIR packing (16 rows x 4 readers per b128) is
// the conflicted geometry. R1's measured-0 geometry = 8 rows x 8 readers,
// distinct chunks per row. Also: all rounds pin at ~37% MfmaUtil because
// LDS demand (reads/MFMA = (mi+ni)/(mi*ni) = 0.75 -> 1152 cyc/CU-step at
// measured 85B/cyc) exceeds the 1024 matrix-cyc. Both fixed together:
//  - wave tile 128x128 (mi=ni=4): ratio 0.5 -> LDS 768 < MFMA 1024 cyc/step
//    (acc=256 regs, 1 wave/SIMD, ONE 4-wave block/CU -- tolerable because
//    sync is 1 barrier + 1 counted vmcnt(8) per 1024 matrix-cyc, and the
//    vmcnt waits on loads issued 2 steps earlier = instant)
//  - row-QUAD LDS packing (plane row j = 4 global rows x 16 k-elems, chunk
//    sq = (row&3)*2 + k8, phys p = sq ^ (j&7)): R1's verified 0-conflict
//    8-rows/8-readers geometry, pre-swizzled global source (T21)
//  - block 256x256, BK=32, 3 slots x 32KB = 96KB LDS
//  - grid 1152 = 8 XCD x 16 bm x 9 (r,bn), bnr fastest (A panel L2-hot)

#define DIM   768
#define NREL  3

typedef __bf16 bf16x8 __attribute__((ext_vector_type(8)));
typedef float  f32x4  __attribute__((ext_vector_type(4)));
typedef float  f32x16 __attribute__((ext_vector_type(16)));
typedef unsigned short us4 __attribute__((ext_vector_type(4)));
typedef unsigned short us8 __attribute__((ext_vector_type(8)));

// ---------------- helpers ----------------
__device__ __forceinline__ float bfs(unsigned short u){
  union { unsigned u; float f; } v; v.u = ((unsigned)u) << 16; return v.f;
}
__device__ __forceinline__ float bfl(unsigned x){
  union { unsigned u; float f; } v; v.u = x << 16; return v.f;
}
__device__ __forceinline__ float bfh(unsigned x){
  union { unsigned u; float f; } v; v.u = x & 0xffff0000u; return v.f;
}
__device__ __forceinline__ unsigned short f2bf(float f){   // RNE
  union { float f; unsigned u; } v; v.f = f;
  unsigned r = v.u + 0x7fffu + ((v.u >> 16) & 1u);
  return (unsigned short)(r >> 16);
}
__device__ __forceinline__ unsigned pck(float a, float b){
  return (unsigned)f2bf(a) | ((unsigned)f2bf(b) << 16);
}
__device__ __forceinline__ float ldf(const void* p, size_t i, int is32){
  return is32 ? ((const float*)p)[i] : bfs(((const unsigned short*)p)[i]);
}
__device__ __forceinline__ int ldi(const void* p, size_t i, int is64){
  return is64 ? ((const int*)p)[2 * i] : ((const int*)p)[i];
}

typedef __attribute__((address_space(1))) void gvoid_t;
typedef __attribute__((address_space(3))) void lvoid_t;
__device__ __forceinline__ void gload16(const void* g, void* l){
  __builtin_amdgcn_global_load_lds((gvoid_t*)g, (lvoid_t*)l, 16, 0, 0);
}

template<int H>
__device__ __forceinline__ float sel(const float (&a)[H], int h){
  float v = a[0];
#pragma unroll
  for (int i = 1; i < H; ++i) v = (h == i) ? a[i] : v;
  return v;
}

// ---------------- dtype detection ----------------
__global__ void detect_kernel(const unsigned short* __restrict__ xu,
                              const unsigned* __restrict__ eiu,
                              const unsigned* __restrict__ etyu,
                              int* __restrict__ flags){
  __shared__ int s_weird, s_ei, s_ety;
  int t = threadIdx.x;
  if (t == 0){ s_weird = 0; s_ei = 0; s_ety = 0; }
  __syncthreads();
  unsigned short u = xu[2 * t];
  int ex = (u >> 7) & 0xff;
  if (ex >= 0xF0 || ex <= 0x40) atomicAdd(&s_weird, 1);
  if (t < 128){
    if (eiu[2 * t + 1]  != 0) atomicAdd(&s_ei, 1);
    if (etyu[2 * t + 1] != 0) atomicAdd(&s_ety, 1);
  }
  __syncthreads();
  if (t == 0){
    flags[0] = (s_weird > 16) ? 1 : 0;
    flags[1] = (s_ei  == 0) ? 1 : 0;
    flags[2] = (s_ety == 0) ? 1 : 0;
  }
}

// ---------------- x -> internal bf16 ----------------
__global__ void convert_x(const void* __restrict__ xin, unsigned short* __restrict__ xb,
                          const int* __restrict__ flags, int n4){
  int i = blockIdx.x * blockDim.x + threadIdx.x;
  if (i >= n4) return;
  if (flags[0]){
    float4 v = ((const float4*)xin)[i];
    us4 o; o.x = f2bf(v.x); o.y = f2bf(v.y); o.z = f2bf(v.z); o.w = f2bf(v.w);
    ((us4*)xb)[i] = o;
  } else {
    ((us4*)xb)[i] = ((const us4*)xin)[i];
  }
}

// ---------------- CSR build ----------------
__global__ void hist_kernel(const void* __restrict__ ei, int* __restrict__ counts,
                            const int* __restrict__ flags, int E){
  int e = blockIdx.x * blockDim.x + threadIdx.x;
  if (e < E) atomicAdd(&counts[ldi(ei, (size_t)E + e, flags[1])], 1);
}

__global__ void scan_kernel(const int* __restrict__ counts, int* __restrict__ offs,
                            int* __restrict__ cursor, int n){
  __shared__ int s[1024];
  int tid = threadIdx.x;
  int base = tid * 32;
  int loc[32];
  int run = 0;
#pragma unroll
  for (int i = 0; i < 32; ++i){ loc[i] = run; run += counts[base + i]; }
  s[tid] = run;
  __syncthreads();
  for (int off = 1; off < 1024; off <<= 1){
    int add = (tid >= off) ? s[tid - off] : 0;
    __syncthreads();
    s[tid] += add;
    __syncthreads();
  }
  int ex = (tid == 0) ? 0 : s[tid - 1];
#pragma unroll
  for (int i = 0; i < 32; ++i){
    int o = ex + loc[i];
    offs[base + i]   = o;
    cursor[base + i] = o;
  }
  if (tid == 1023) offs[n] = s[1023];
}

__global__ void scatter_kernel(const void* __restrict__ ei, const void* __restrict__ ety,
                               int* __restrict__ cursor, int* __restrict__ payload,
                               const int* __restrict__ flags, int E){
  int e = blockIdx.x * blockDim.x + threadIdx.x;
  if (e < E){
    int dst = ldi(ei, (size_t)E + e, flags[1]);
    int src = ldi(ei, (size_t)e,     flags[1]);
    int et  = ldi(ety, (size_t)e,    flags[2]);
    int pos = atomicAdd(&cursor[dst], 1);
    payload[pos] = (et << 16) | src;
  }
}

// ---------------- W transpose+convert ----------------
__global__ void transpose_w(const void* __restrict__ W, unsigned short* __restrict__ Wt,
                            const int* __restrict__ flags){
  __shared__ unsigned short t[32][33];
  int is32 = flags[0];
  int r = blockIdx.z;
  size_t Wb = (size_t)r * DIM * DIM;
  unsigned short* Wd = Wt + (size_t)r * DIM * DIM;
  int tx = threadIdx.x, ty = threadIdx.y;
  int x  = blockIdx.x * 32 + tx;
  int y0 = blockIdx.y * 32;
#pragma unroll
  for (int i = 0; i < 32; i += 8)
    t[ty + i][tx] = f2bf(ldf(W, Wb + (size_t)(y0 + ty + i) * DIM + x, is32));
  __syncthreads();
  int x2 = blockIdx.y * 32 + tx;
  int y2 = blockIdx.x * 32;
#pragma unroll
  for (int i = 0; i < 32; i += 8) Wd[(size_t)(y2 + ty + i) * DIM + x2] = t[tx][ty + i];
}

// ---------------- Wqkb[d][32] (bf16) = [W@q | W@k] per relation ----------------
// col = r*8 + isK*4 + h  (cols 24..31 pad; zeroed by memset before launch)
template<int H>
__global__ void wqk_kernel(const void* __restrict__ W,
                           const void* __restrict__ q, const void* __restrict__ k,
                           unsigned short* __restrict__ Wqkb,
                           const int* __restrict__ flags){
  int is32 = flags[0];
  int wid  = (blockIdx.x * blockDim.x + threadIdx.x) >> 6;
  int lane = threadIdx.x & 63;
  int r = wid / DIM, d = wid % DIM;
  size_t Wrow = ((size_t)r * DIM + d) * DIM;
  float aq[H], ak[H];
#pragma unroll
  for (int h = 0; h < H; ++h){ aq[h] = 0.f; ak[h] = 0.f; }
#pragma unroll
  for (int j = 0; j < 12; ++j){
    int f = j * 64 + lane;
    float wv = ldf(W, Wrow + f, is32);
#pragma unroll
    for (int h = 0; h < H; ++h){
      aq[h] += wv * ldf(q, (size_t)f * H + h, is32);
      ak[h] += wv * ldf(k, (size_t)f * H + h, is32);
    }
  }
#pragma unroll
  for (int h = 0; h < H; ++h){
    for (int off = 32; off; off >>= 1){
      aq[h] += __shfl_xor(aq[h], off);
      ak[h] += __shfl_xor(ak[h], off);
    }
  }
  if (lane == 0){
#pragma unroll
    for (int h = 0; h < H; ++h){
      Wqkb[(size_t)d * 32 + r * 8 + h]     = f2bf(aq[h]);
      Wqkb[(size_t)d * 32 + r * 8 + 4 + h] = f2bf(ak[h]);
    }
  }
}

// ---------------- pack Wqkb into MFMA B-fragment order ----------------
// Bpk[t][nt][lane] = 8 bf16: Wqkb[t*32 + (lane>>4)*8 + j][nt*16 + (lane&15)]
__global__ void pack_b(const unsigned short* __restrict__ Wqkb, unsigned short* __restrict__ Bpk){
  int i = blockIdx.x * 256 + threadIdx.x;   // 24*2*64 = 3072
  if (i >= 3072) return;
  int lane = i & 63, nt = (i >> 6) & 1, t = i >> 7;
  int kb = t * 32 + (lane >> 4) * 8;
  int col = nt * 16 + (lane & 15);
  us8 v;
#pragma unroll
  for (int j = 0; j < 8; ++j) v[j] = Wqkb[(size_t)(kb + j) * 32 + col];
  ((us8*)Bpk)[i] = v;
}

// ---------------- qn/kn via skinny MFMA: [N,768]@[768,32] ----------------
// output layout qn[r][n][4], kn[r][n][4] fp32 (H=4 uses all, H=1 uses h=0)
__global__ void __launch_bounds__(256)
qnkn_mfma(const unsigned short* __restrict__ X, const unsigned short* __restrict__ Bpk,
          float* __restrict__ qn, float* __restrict__ kn, int nN){
  int wv = threadIdx.x >> 6, lane = threadIdx.x & 63;
  int row0 = (blockIdx.x * 4 + wv) * 16;
  int ar = lane & 15, quad = lane >> 4;
  const unsigned short* Arow = X + (size_t)(row0 + ar) * DIM + quad * 8;
  const bf16x8* Bp = (const bf16x8*)Bpk;
  f32x4 acc0 = {0.f,0.f,0.f,0.f}, acc1 = {0.f,0.f,0.f,0.f};
#pragma unroll
  for (int t = 0; t < 24; ++t){
    bf16x8 a  = *(const bf16x8*)(Arow + t * 32);
    bf16x8 b0 = Bp[(t * 2 + 0) * 64 + lane];
    bf16x8 b1 = Bp[(t * 2 + 1) * 64 + lane];
    acc0 = __builtin_amdgcn_mfma_f32_16x16x32_bf16(a, b0, acc0, 0, 0, 0);
    acc1 = __builtin_amdgcn_mfma_f32_16x16x32_bf16(a, b1, acc1, 0, 0, 0);
  }
#pragma unroll
  for (int nt = 0; nt < 2; ++nt){
    int col = nt * 16 + (lane & 15);
    if (col < 24){
      int r = col >> 3, isK = (col >> 2) & 1, h = col & 3;
      float* bp = isK ? kn : qn;
      f32x4 a = nt ? acc1 : acc0;
#pragma unroll
      for (int j = 0; j < 4; ++j){
        int row = row0 + quad * 4 + j;
        bp[((size_t)r * nN + row) * 4 + h] = a[j];
      }
    }
  }
}

// ---------------- MFMA GEMM: C[r]=A@W[r], 32x32x16, 256x256 tile, 4 fat waves --
// 4 waves (2x2), wave tile 128x128 = 4x4 tiles of 32x32, acc[4][4] f32x16.
// LDS slot (32KB) = A[kk0]8KB, A[kk1]8KB, B[kk0]8KB, B[kk1]8KB; each sub-plane
// 64 plane-rows x 128B; plane row j holds global rows {4j..4j+3} x 16 k-elems;
// logical chunk sq = (row&3)*2 + k8 at phys chunk p = sq ^ (j&7)  -- the
// R1-verified 0-conflict geometry (8 rows x 8 readers, distinct chunks/row).
// Per K-step(32): 8 gload_lds + 16 ds_read_b128 + 32 MFMA (1024 matrix-cyc)
// against ONE vmcnt(8) + ONE barrier. 3 slots; STAGE(t+2) issued first.
#define MF(A_, B_, C_) __builtin_amdgcn_mfma_f32_32x32x16_bf16(A_, B_, C_, 0, 0, 0)

#define STAGE(SW, KW) {                                                        \
  gload16(gAa + (KW),                 &lds[(SW)*32768 +         wB]);          \
  gload16(gAa + (KW) + 16,            &lds[(SW)*32768 +  8192 + wB]);          \
  gload16(gAa + 128*DIM + (KW),       &lds[(SW)*32768 +  4096 + wB]);          \
  gload16(gAa + 128*DIM + (KW) + 16,  &lds[(SW)*32768 + 12288 + wB]);          \
  gload16(gBb + (KW),                 &lds[(SW)*32768 + 16384 + wB]);          \
  gload16(gBb + (KW) + 16,            &lds[(SW)*32768 + 24576 + wB]);          \
  gload16(gBb + 128*DIM + (KW),       &lds[(SW)*32768 + 20480 + wB]);          \
  gload16(gBb + 128*DIM + (KW) + 16,  &lds[(SW)*32768 + 28672 + wB]);          \
}

#define STEP(S, KW, DOST) {                                                    \
  if (DOST) STAGE(((S)+2)%3, KW);                                              \
  bf16x8 a00 = *(const bf16x8*)&lds[(S)*32768 + aoff];                         \
  bf16x8 a01 = *(const bf16x8*)&lds[(S)*32768 + aoff + 1024];                  \
  bf16x8 a02 = *(const bf16x8*)&lds[(S)*32768 + aoff + 2048];                  \
  bf16x8 a03 = *(const bf16x8*)&lds[(S)*32768 + aoff + 3072];                  \
  bf16x8 b00 = *(const bf16x8*)&lds[(S)*32768 + boff];                         \
  bf16x8 b01 = *(const bf16x8*)&lds[(S)*32768 + boff + 1024];                  \
  bf16x8 b02 = *(const bf16x8*)&lds[(S)*32768 + boff + 2048];                  \
  bf16x8 b03 = *(const bf16x8*)&lds[(S)*32768 + boff + 3072];                  \
  bf16x8 a10 = *(const bf16x8*)&lds[(S)*32768 + 8192 + aoff];                  \
  bf16x8 a11 = *(const bf16x8*)&lds[(S)*32768 + 8192 + aoff + 1024];           \
  bf16x8 a12 = *(const bf16x8*)&lds[(S)*32768 + 8192 + aoff + 2048];           \
  bf16x8 a13 = *(const bf16x8*)&lds[(S)*32768 + 8192 + aoff + 3072];           \
  bf16x8 b10 = *(const bf16x8*)&lds[(S)*32768 + 8192 + boff];                  \
  bf16x8 b11 = *(const bf16x8*)&lds[(S)*32768 + 8192 + boff + 1024];           \
  bf16x8 b12 = *(const bf16x8*)&lds[(S)*32768 + 8192 + boff + 2048];           \
  bf16x8 b13 = *(const bf16x8*)&lds[(S)*32768 + 8192 + boff + 3072];           \
  __builtin_amdgcn_s_setprio(1);                                               \
  acc[0][0] = MF(a00, b00, acc[0][0]); acc[0][1] = MF(a00, b01, acc[0][1]);    \
  acc[0][2] = MF(a00, b02, acc[0][2]); acc[0][3] = MF(a00, b03, acc[0][3]);    \
  acc[1][0] = MF(a01, b00, acc[1][0]); acc[1][1] = MF(a01, b01, acc[1][1]);    \
  acc[1][2] = MF(a01, b02, acc[1][2]); acc[1][3] = MF(a01, b03, acc[1][3]);    \
  acc[2][0] = MF(a02, b00, acc[2][0]); acc[2][1] = MF(a02, b01, acc[2][1]);    \
  acc[2][2] = MF(a02, b02, acc[2][2]); acc[2][3] = MF(a02, b03, acc[2][3]);    \
  acc[3][0] = MF(a03, b00, acc[3][0]); acc[3][1] = MF(a03, b01, acc[3][1]);    \
  acc[3][2] = MF(a03, b02, acc[3][2]); acc[3][3] = MF(a03, b03, acc[3][3]);    \
  acc[0][0] = MF(a10, b10, acc[0][0]); acc[0][1] = MF(a10, b11, acc[0][1]);    \
  acc[0][2] = MF(a10, b12, acc[0][2]); acc[0][3] = MF(a10, b13, acc[0][3]);    \
  acc[1][0] = MF(a11, b10, acc[1][0]); acc[1][1] = MF(a11, b11, acc[1][1]);    \
  acc[1][2] = MF(a11, b12, acc[1][2]); acc[1][3] = MF(a11, b13, acc[1][3]);    \
  acc[2][0] = MF(a12, b10, acc[2][0]); acc[2][1] = MF(a12, b11, acc[2][1]);    \
  acc[2][2] = MF(a12, b12, acc[2][2]); acc[2][3] = MF(a12, b13, acc[2][3]);    \
  acc[3][0] = MF(a13, b10, acc[3][0]); acc[3][1] = MF(a13, b11, acc[3][1]);    \
  acc[3][2] = MF(a13, b12, acc[3][2]); acc[3][3] = MF(a13, b13, acc[3][3]);    \
  __builtin_amdgcn_s_setprio(0);                                               \
}
#define W8 { asm volatile("s_waitcnt vmcnt(8)" ::: "memory"); __builtin_amdgcn_s_barrier(); }

__global__ void __launch_bounds__(256, 1)
gemm_bf16(const unsigned short* __restrict__ A,
          const unsigned short* __restrict__ Bt,
          unsigned short* __restrict__ C, int M){
  __shared__ __align__(16) unsigned char lds[98304];   // 3 slots x 32KB
  const int K = DIM;
  int i = blockIdx.x;
  int xcd = i & 7, s = i >> 3;            // s in 0..143
  int bm  = xcd * 16 + s / 9;             // 0..127 (M/256 tiles)
  int bnr = s % 9;
  int rrel = bnr / 3, bn = bnr % 3;       // 3 N-tiles of 256 per relation
  int tid = threadIdx.x;
  int w = tid >> 6, lane = tid & 63;
  int wr = w >> 1, wc = w & 1;            // 2x2 wave grid, wave tile 128x128
  int lo = lane & 31, hi = lane >> 5;

  // frag-read constants (row-quad packing): plane row j = base + (lo>>2),
  // logical chunk sq = (lo&3)*2 + hi, phys p = sq ^ ((lo>>2)&7)
  int jq = lo >> 2;
  int p  = (((lo & 3) << 1) | hi) ^ (jq & 7);
  int aoff =         (wr * 32 + jq) * 128 + p * 16;   // + mi*1024, + kk*8192
  int boff = 16384 + (wc * 32 + jq) * 128 + p * 16;   // + ni*1024, + kk*8192

  // staging constants: thread t writes phys chunk p=t&7 at plane row
  // j = it*32 + (t>>3); logical sq = p ^ (j&7) -> global row 4j + (sq>>1),
  // k-elem offset (sq&1)*8 within the 16-elem slice
  int sq   = (tid & 7) ^ ((tid >> 3) & 7);
  int srow = 4 * (tid >> 3) + (sq >> 1);         // 0..127
  const unsigned short* gAa = A  + ((size_t)bm * 256 + srow) * K + (sq & 1) * 8;
  const unsigned short* gBb = Bt + ((size_t)(rrel * DIM + bn * 256 + srow)) * K + (sq & 1) * 8;
  int wB = w * 1024;                             // wave-uniform LDS dest base

  f32x16 acc[4][4];
  f32x16 zz = {0.f,0.f,0.f,0.f,0.f,0.f,0.f,0.f,0.f,0.f,0.f,0.f,0.f,0.f,0.f,0.f};
#pragma unroll
  for (int a = 0; a < 4; ++a)
#pragma unroll
    for (int b = 0; b < 4; ++b) acc[a][b] = zz;

  // prologue: stage slots 0 (k=0) and 1 (k=32); wait slot0 (slot1 in flight)
  STAGE(0, 0); STAGE(1, 32);
  W8;

#pragma unroll 1
  for (int t7 = 0; t7 < 7; ++t7){          // K-steps 0..20 (slot = t%3)
    int kb = t7 * 96;
    STEP(0, kb + 64,  1); W8;
    STEP(1, kb + 96,  1); W8;
    STEP(2, kb + 128, 1); W8;
  }
  STEP(0, 736, 1); W8;                     // t=21, stages t=23 -> slot 2
  STEP(1, 0, 0);                           // t=22
  asm volatile("s_waitcnt vmcnt(0)" ::: "memory");
  __builtin_amdgcn_s_barrier();
  STEP(2, 0, 0);                           // t=23

  unsigned short* Cg = C + ((size_t)rrel * M + (size_t)bm * 256) * DIM + bn * 256;
#pragma unroll
  for (int mi = 0; mi < 4; ++mi)
#pragma unroll
    for (int ni = 0; ni < 4; ++ni)
#pragma unroll
      for (int rg = 0; rg < 4; ++rg)
#pragma unroll
        for (int j = 0; j < 4; ++j){
          int row = wr * 128 + mi * 32 + rg * 8 + hi * 4 + j;
          int col = wc * 128 + ni * 32 + lo;
          Cg[(size_t)row * DIM + col] = f2bf(acc[mi][ni][rg * 4 + j]);
        }
}

// ---------------- per-node attention + aggregation (one wave per node) ----------------
// Per-wave LDS for chunk payload/weights (no inner-loop shuffles); gathers
// batched 4-wide for MLP (12 independent loads in flight).
template<int H, bool ELU, bool OUT32>
__global__ void __launch_bounds__(256)
agg_kernel(const unsigned short* __restrict__ xr,
           const float* __restrict__ qn, const float* __restrict__ kn,
           const int* __restrict__ offs, const int* __restrict__ payload,
           const void* __restrict__ bias,
           void* __restrict__ outp,
           const int* __restrict__ flags, int nN, int E){
  const int WH = (H == 4) ? 4 : 1;
  __shared__ int   pay_s[4][64];
  __shared__ float w_s[4][64 * WH];
  int is32 = flags[0];
  int wv   = threadIdx.x >> 6;
  int lane = threadIdx.x & 63;
  int n = blockIdx.x * 4 + wv;
  int rs = offs[n], re = offs[n + 1];
  rs = max(rs, 0); re = min(re, E);
  const int myh = (H == 1) ? 0 : (lane >> 4);   // OUTC=192: lane*12/192 = lane/16

  float m_run[H], z_run[H], acc[12];
#pragma unroll
  for (int h = 0; h < H; ++h){ m_run[h] = -__builtin_inff(); z_run[h] = 0.f; }
#pragma unroll
  for (int i = 0; i < 12; ++i) acc[i] = 0.f;

  for (int base = rs; base < re; base += 64){
    int dc = min(64, re - base);
    int pay = 0;
    float al[H];
#pragma unroll
    for (int h = 0; h < H; ++h) al[h] = -__builtin_inff();
    if (lane < dc){
      pay = payload[base + lane];
      int et = pay >> 16, src = pay & 0xffff;
      if (H == 4){
        f32x4 qv = *(const f32x4*)(qn + ((size_t)et * nN + n)   * 4);
        f32x4 kv = *(const f32x4*)(kn + ((size_t)et * nN + src) * 4);
#pragma unroll
        for (int h = 0; h < H; ++h){
          float a = qv[h & 3] + kv[h & 3];
          al[h] = (a > 0.f) ? a : 0.2f * a;
        }
      } else {
        float a = qn[((size_t)et * nN + n) * 4] + kn[((size_t)et * nN + src) * 4];
        al[0] = (a > 0.f) ? a : 0.2f * a;
      }
    }
    // online-softmax chunk update
    float scs[H], wgt[H];
#pragma unroll
    for (int h = 0; h < H; ++h){
      float v = al[h];
      for (int off = 32; off; off >>= 1) v = fmaxf(v, __shfl_xor(v, off));
      float nm = fmaxf(m_run[h], v);
      scs[h] = (m_run[h] == -__builtin_inff()) ? 0.f : expf(m_run[h] - nm);
      m_run[h] = nm;
      wgt[h] = (lane < dc) ? expf(al[h] - nm) : 0.f;
      float s = wgt[h];
      for (int off = 32; off; off >>= 1) s += __shfl_xor(s, off);
      z_run[h] = z_run[h] * scs[h] + s;
    }
    float msc = sel<H>(scs, myh);
#pragma unroll
    for (int i = 0; i < 12; ++i) acc[i] *= msc;

    // stash chunk data in per-wave LDS (same-wave DS ops are in-order)
    if (lane < dc){
      pay_s[wv][lane] = pay;
#pragma unroll
      for (int h = 0; h < WH; ++h) w_s[wv][lane * WH + h] = wgt[h];
    }

    // batched gather-accumulate: 4 edges -> 12 loads in flight
    for (int j0 = 0; j0 < dc; j0 += 4){
      uint2 c[4][3];
      float w4[4];
#pragma unroll
      for (int u = 0; u < 4; ++u){
        int jc = j0 + u;
        int ok = jc < dc;
        int jl2 = ok ? jc : j0;
        int pj = pay_s[wv][jl2];
        float ww = w_s[wv][jl2 * WH + ((H == 1) ? 0 : myh)];
        w4[u] = ok ? ww : 0.f;
        int et = pj >> 16, src = pj & 0xffff;
        const uint2* rp = (const uint2*)(xr + ((size_t)et * nN + src) * DIM + lane * 12);
        c[u][0] = rp[0]; c[u][1] = rp[1]; c[u][2] = rp[2];
      }
#pragma unroll
      for (int u = 0; u < 4; ++u){
        float wj = w4[u];
        acc[0]  += wj * bfl(c[u][0].x); acc[1]  += wj * bfh(c[u][0].x);
        acc[2]  += wj * bfl(c[u][0].y); acc[3]  += wj * bfh(c[u][0].y);
        acc[4]  += wj * bfl(c[u][1].x); acc[5]  += wj * bfh(c[u][1].x);
        acc[6]  += wj * bfl(c[u][1].y); acc[7]  += wj * bfh(c[u][1].y);
        acc[8]  += wj * bfl(c[u][2].x); acc[9]  += wj * bfh(c[u][2].x);
        acc[10] += wj * bfl(c[u][2].y); acc[11] += wj * bfh(c[u][2].y);
      }
    }
  }

  float inv = 1.0f / (sel<H>(z_run, myh) + 1e-16f);
  float o[12];
#pragma unroll
  for (int i = 0; i < 12; ++i){
    float v = acc[i] * inv + ldf(bias, (size_t)lane * 12 + i, is32);
    if (ELU) v = (v > 0.f) ? v : (expf(v) - 1.f);
    o[i] = v;
  }
  if (OUT32 && is32){
    float* op = (float*)outp + (size_t)n * DIM + lane * 12;
    float4 f0 = {o[0], o[1], o[2],  o[3]};
    float4 f1 = {o[4], o[5], o[6],  o[7]};
    float4 f2 = {o[8], o[9], o[10], o[11]};
    ((float4*)op)[0] = f0; ((float4*)op)[1] = f1; ((float4*)op)[2] = f2;
  } else {
    uint2* op = (uint2*)((unsigned short*)outp + (size_t)n * DIM + lane * 12);
    uint2 s0, s1, s2;
    s0.x = pck(o[0], o[1]);  s0.y = pck(o[2], o[3]);
    s1.x = pck(o[4], o[5]);  s1.y = pck(o[6], o[7]);
    s2.x = pck(o[8], o[9]);  s2.y = pck(o[10], o[11]);
    op[0] = s0; op[1] = s1; op[2] = s2;
  }
}

// ---------------- launcher ----------------
extern "C" void kernel_launch(void* const* d_in, const int* in_sizes, int n_in,
                              void* d_out, int out_size, void* d_ws, size_t ws_size,
                              hipStream_t stream){
  const void* x   = d_in[0];
  const void* ei  = d_in[1];
  const void* ety = d_in[2];
  const void* W1  = d_in[3];
  const void* q1  = d_in[4];
  const void* k1  = d_in[5];
  const void* b1  = d_in[6];
  const void* W2  = d_in[7];
  const void* q2  = d_in[8];
  const void* k2  = d_in[9];
  const void* b2  = d_in[10];

  int nN = in_sizes[0] / DIM;   // 32768
  int E  = in_sizes[2];         // 160000

  char* ws = (char*)d_ws;
  size_t off = 0;
  auto alloc = [&](size_t bytes) -> void* {
    void* p = ws + off;
    off += (bytes + 255) & ~(size_t)255;
    return p;
  };
  unsigned short* xr   = (unsigned short*)alloc((size_t)NREL * nN * DIM * 2);
  unsigned short* xb   = (unsigned short*)alloc((size_t)nN * DIM * 2);
  unsigned short* h    = (unsigned short*)alloc((size_t)nN * DIM * 2);
  unsigned short* Wt   = (unsigned short*)alloc((size_t)NREL * DIM * DIM * 2);
  unsigned short* Wqkb = (unsigned short*)alloc((size_t)DIM * 32 * 2);
  unsigned short* Bpk  = (unsigned short*)alloc((size_t)3072 * 16);
  float* qn  = (float*)alloc((size_t)NREL * nN * 4 * 4);
  float* kn  = (float*)alloc((size_t)NREL * nN * 4 * 4);
  int* offs    = (int*)alloc((size_t)(nN + 1) * 4);
  int* cursor  = (int*)alloc((size_t)nN * 4);
  int* counts  = (int*)alloc((size_t)nN * 4);
  int* payload = (int*)alloc((size_t)E * 4);
  int* flags   = (int*)alloc(16);

  detect_kernel<<<1, 256, 0, stream>>>((const unsigned short*)x, (const unsigned*)ei,
                                       (const unsigned*)ety, flags);
  convert_x<<<(nN * DIM / 4 + 255) / 256, 256, 0, stream>>>(x, xb, flags, nN * DIM / 4);

  hipMemsetAsync(counts, 0, (size_t)nN * 4, stream);
  hist_kernel<<<(E + 255) / 256, 256, 0, stream>>>(ei, counts, flags, E);
  scan_kernel<<<1, 1024, 0, stream>>>(counts, offs, cursor, nN);
  scatter_kernel<<<(E + 255) / 256, 256, 0, stream>>>(ei, ety, cursor, payload, flags, E);

  dim3 tg(DIM / 32, DIM / 32, NREL), tb(32, 8);
  int gemm_blocks = 8 * (16 * 9);   // 1152: 128 m-tiles x 9 (r,bn)

  // ---- layer 1 (H=4, ELU) ----
  transpose_w<<<tg, tb, 0, stream>>>(W1, Wt, flags);
  hipMemsetAsync(Wqkb, 0, (size_t)DIM * 32 * 2, stream);
  wqk_kernel<4><<<(NREL * DIM) / 4, 256, 0, stream>>>(W1, q1, k1, Wqkb, flags);
  pack_b<<<12, 256, 0, stream>>>(Wqkb, Bpk);
  qnkn_mfma<<<nN / 64, 256, 0, stream>>>(xb, Bpk, qn, kn, nN);
  gemm_bf16<<<gemm_blocks, 256, 0, stream>>>(xb, Wt, xr, nN);
  agg_kernel<4, true, false><<<nN / 4, 256, 0, stream>>>(xr, qn, kn, offs, payload, b1, h,
                                                         flags, nN, E);

  // ---- layer 2 (H=1, no activation) ----
  transpose_w<<<tg, tb, 0, stream>>>(W2, Wt, flags);
  hipMemsetAsync(Wqkb, 0, (size_t)DIM * 32 * 2, stream);
  wqk_kernel<1><<<(NREL * DIM) / 4, 256, 0, stream>>>(W2, q2, k2, Wqkb, flags);
  pack_b<<<12, 256, 0, stream>>>(Wqkb, Bpk);
  qnkn_mfma<<<nN / 64, 256, 0, stream>>>(h, Bpk, qn, kn, nN);
  gemm_bf16<<<gemm_blocks, 256, 0, stream>>>(h, Wt, xr, nN);
  agg_kernel<1, false, true><<<nN / 4, 256, 0, stream>>>(xr, qn, kn, offs, payload, b2,
                                                         d_out, flags, nN, E);
}

// Round 7
// 675.653 us; speedup vs baseline: 1.0623x; 1.0623x over previous
//
#include <hip/hip_runtime.h>

// RGAT encoder, 2 layers. N=32768, E=160000, DIM=768, R=3, heads 4 then 1.
// Round 11 (from 662 us): R8-R10's 32x32 gemm variants all carry +4cyc/instr
// LDS conflicts regardless of swizzle (3 failed predictions) and the fat-tile
// 1-block/CU structure is bubble-bound. REVERTED gemm byte-for-byte to the
// best-measured version (R6/round-1: 128x256, BK=32, 64x64 wave tiles,
// 3-slot counted-vmcnt pipe, 2 blocks/CU, 132us, 0 conflicts, Occ 40%).
// This round's single change: agg gather batch 4 -> 8 edges (24 loads in
// flight; avg deg 4.9 -> 94% of nodes finish in ONE iteration instead of 2
// serial L3 round-trips). If agg is latency-bound this is +10-20%; if
// L3-BW-bound it's a clean null -> next round attacks bytes, with counters.

#define DIM   768
#define NREL  3

typedef __bf16 bf16x8 __attribute__((ext_vector_type(8)));
typedef float  f32x4  __attribute__((ext_vector_type(4)));
typedef unsigned short us4 __attribute__((ext_vector_type(4)));
typedef unsigned short us8 __attribute__((ext_vector_type(8)));

// ---------------- helpers ----------------
__device__ __forceinline__ float bfs(unsigned short u){
  union { unsigned u; float f; } v; v.u = ((unsigned)u) << 16; return v.f;
}
__device__ __forceinline__ float bfl(unsigned x){
  union { unsigned u; float f; } v; v.u = x << 16; return v.f;
}
__device__ __forceinline__ float bfh(unsigned x){
  union { unsigned u; float f; } v; v.u = x & 0xffff0000u; return v.f;
}
__device__ __forceinline__ unsigned short f2bf(float f){   // RNE
  union { float f; unsigned u; } v; v.f = f;
  unsigned r = v.u + 0x7fffu + ((v.u >> 16) & 1u);
  return (unsigned short)(r >> 16);
}
__device__ __forceinline__ unsigned pck(float a, float b){
  return (unsigned)f2bf(a) | ((unsigned)f2bf(b) << 16);
}
__device__ __forceinline__ float ldf(const void* p, size_t i, int is32){
  return is32 ? ((const float*)p)[i] : bfs(((const unsigned short*)p)[i]);
}
__device__ __forceinline__ int ldi(const void* p, size_t i, int is64){
  return is64 ? ((const int*)p)[2 * i] : ((const int*)p)[i];
}

typedef __attribute__((address_space(1))) void gvoid_t;
typedef __attribute__((address_space(3))) void lvoid_t;
__device__ __forceinline__ void gload16(const void* g, void* l){
  __builtin_amdgcn_global_load_lds((gvoid_t*)g, (lvoid_t*)l, 16, 0, 0);
}

template<int H>
__device__ __forceinline__ float sel(const float (&a)[H], int h){
  float v = a[0];
#pragma unroll
  for (int i = 1; i < H; ++i) v = (h == i) ? a[i] : v;
  return v;
}

// ---------------- dtype detection ----------------
__global__ void detect_kernel(const unsigned short* __restrict__ xu,
                              const unsigned* __restrict__ eiu,
                              const unsigned* __restrict__ etyu,
                              int* __restrict__ flags){
  __shared__ int s_weird, s_ei, s_ety;
  int t = threadIdx.x;
  if (t == 0){ s_weird = 0; s_ei = 0; s_ety = 0; }
  __syncthreads();
  unsigned short u = xu[2 * t];
  int ex = (u >> 7) & 0xff;
  if (ex >= 0xF0 || ex <= 0x40) atomicAdd(&s_weird, 1);
  if (t < 128){
    if (eiu[2 * t + 1]  != 0) atomicAdd(&s_ei, 1);
    if (etyu[2 * t + 1] != 0) atomicAdd(&s_ety, 1);
  }
  __syncthreads();
  if (t == 0){
    flags[0] = (s_weird > 16) ? 1 : 0;
    flags[1] = (s_ei  == 0) ? 1 : 0;
    flags[2] = (s_ety == 0) ? 1 : 0;
  }
}

// ---------------- x -> internal bf16 ----------------
__global__ void convert_x(const void* __restrict__ xin, unsigned short* __restrict__ xb,
                          const int* __restrict__ flags, int n4){
  int i = blockIdx.x * blockDim.x + threadIdx.x;
  if (i >= n4) return;
  if (flags[0]){
    float4 v = ((const float4*)xin)[i];
    us4 o; o.x = f2bf(v.x); o.y = f2bf(v.y); o.z = f2bf(v.z); o.w = f2bf(v.w);
    ((us4*)xb)[i] = o;
  } else {
    ((us4*)xb)[i] = ((const us4*)xin)[i];
  }
}

// ---------------- CSR build ----------------
__global__ void hist_kernel(const void* __restrict__ ei, int* __restrict__ counts,
                            const int* __restrict__ flags, int E){
  int e = blockIdx.x * blockDim.x + threadIdx.x;
  if (e < E) atomicAdd(&counts[ldi(ei, (size_t)E + e, flags[1])], 1);
}

__global__ void scan_kernel(const int* __restrict__ counts, int* __restrict__ offs,
                            int* __restrict__ cursor, int n){
  __shared__ int s[1024];
  int tid = threadIdx.x;
  int base = tid * 32;
  int loc[32];
  int run = 0;
#pragma unroll
  for (int i = 0; i < 32; ++i){ loc[i] = run; run += counts[base + i]; }
  s[tid] = run;
  __syncthreads();
  for (int off = 1; off < 1024; off <<= 1){
    int add = (tid >= off) ? s[tid - off] : 0;
    __syncthreads();
    s[tid] += add;
    __syncthreads();
  }
  int ex = (tid == 0) ? 0 : s[tid - 1];
#pragma unroll
  for (int i = 0; i < 32; ++i){
    int o = ex + loc[i];
    offs[base + i]   = o;
    cursor[base + i] = o;
  }
  if (tid == 1023) offs[n] = s[1023];
}

__global__ void scatter_kernel(const void* __restrict__ ei, const void* __restrict__ ety,
                               int* __restrict__ cursor, int* __restrict__ payload,
                               const int* __restrict__ flags, int E){
  int e = blockIdx.x * blockDim.x + threadIdx.x;
  if (e < E){
    int dst = ldi(ei, (size_t)E + e, flags[1]);
    int src = ldi(ei, (size_t)e,     flags[1]);
    int et  = ldi(ety, (size_t)e,    flags[2]);
    int pos = atomicAdd(&cursor[dst], 1);
    payload[pos] = (et << 16) | src;
  }
}

// ---------------- W transpose+convert ----------------
__global__ void transpose_w(const void* __restrict__ W, unsigned short* __restrict__ Wt,
                            const int* __restrict__ flags){
  __shared__ unsigned short t[32][33];
  int is32 = flags[0];
  int r = blockIdx.z;
  size_t Wb = (size_t)r * DIM * DIM;
  unsigned short* Wd = Wt + (size_t)r * DIM * DIM;
  int tx = threadIdx.x, ty = threadIdx.y;
  int x  = blockIdx.x * 32 + tx;
  int y0 = blockIdx.y * 32;
#pragma unroll
  for (int i = 0; i < 32; i += 8)
    t[ty + i][tx] = f2bf(ldf(W, Wb + (size_t)(y0 + ty + i) * DIM + x, is32));
  __syncthreads();
  int x2 = blockIdx.y * 32 + tx;
  int y2 = blockIdx.x * 32;
#pragma unroll
  for (int i = 0; i < 32; i += 8) Wd[(size_t)(y2 + ty + i) * DIM + x2] = t[tx][ty + i];
}

// ---------------- Wqkb[d][32] (bf16) = [W@q | W@k] per relation ----------------
// col = r*8 + isK*4 + h  (cols 24..31 pad; zeroed by memset before launch)
template<int H>
__global__ void wqk_kernel(const void* __restrict__ W,
                           const void* __restrict__ q, const void* __restrict__ k,
                           unsigned short* __restrict__ Wqkb,
                           const int* __restrict__ flags){
  int is32 = flags[0];
  int wid  = (blockIdx.x * blockDim.x + threadIdx.x) >> 6;
  int lane = threadIdx.x & 63;
  int r = wid / DIM, d = wid % DIM;
  size_t Wrow = ((size_t)r * DIM + d) * DIM;
  float aq[H], ak[H];
#pragma unroll
  for (int h = 0; h < H; ++h){ aq[h] = 0.f; ak[h] = 0.f; }
#pragma unroll
  for (int j = 0; j < 12; ++j){
    int f = j * 64 + lane;
    float wv = ldf(W, Wrow + f, is32);
#pragma unroll
    for (int h = 0; h < H; ++h){
      aq[h] += wv * ldf(q, (size_t)f * H + h, is32);
      ak[h] += wv * ldf(k, (size_t)f * H + h, is32);
    }
  }
#pragma unroll
  for (int h = 0; h < H; ++h){
    for (int off = 32; off; off >>= 1){
      aq[h] += __shfl_xor(aq[h], off);
      ak[h] += __shfl_xor(ak[h], off);
    }
  }
  if (lane == 0){
#pragma unroll
    for (int h = 0; h < H; ++h){
      Wqkb[(size_t)d * 32 + r * 8 + h]     = f2bf(aq[h]);
      Wqkb[(size_t)d * 32 + r * 8 + 4 + h] = f2bf(ak[h]);
    }
  }
}

// ---------------- pack Wqkb into MFMA B-fragment order ----------------
// Bpk[t][nt][lane] = 8 bf16: Wqkb[t*32 + (lane>>4)*8 + j][nt*16 + (lane&15)]
__global__ void pack_b(const unsigned short* __restrict__ Wqkb, unsigned short* __restrict__ Bpk){
  int i = blockIdx.x * 256 + threadIdx.x;   // 24*2*64 = 3072
  if (i >= 3072) return;
  int lane = i & 63, nt = (i >> 6) & 1, t = i >> 7;
  int kb = t * 32 + (lane >> 4) * 8;
  int col = nt * 16 + (lane & 15);
  us8 v;
#pragma unroll
  for (int j = 0; j < 8; ++j) v[j] = Wqkb[(size_t)(kb + j) * 32 + col];
  ((us8*)Bpk)[i] = v;
}

// ---------------- qn/kn via skinny MFMA: [N,768]@[768,32] ----------------
// output layout qn[r][n][4], kn[r][n][4] fp32 (H=4 uses all, H=1 uses h=0)
__global__ void __launch_bounds__(256)
qnkn_mfma(const unsigned short* __restrict__ X, const unsigned short* __restrict__ Bpk,
          float* __restrict__ qn, float* __restrict__ kn, int nN){
  int wv = threadIdx.x >> 6, lane = threadIdx.x & 63;
  int row0 = (blockIdx.x * 4 + wv) * 16;
  int ar = lane & 15, quad = lane >> 4;
  const unsigned short* Arow = X + (size_t)(row0 + ar) * DIM + quad * 8;
  const bf16x8* Bp = (const bf16x8*)Bpk;
  f32x4 acc0 = {0.f,0.f,0.f,0.f}, acc1 = {0.f,0.f,0.f,0.f};
#pragma unroll
  for (int t = 0; t < 24; ++t){
    bf16x8 a  = *(const bf16x8*)(Arow + t * 32);
    bf16x8 b0 = Bp[(t * 2 + 0) * 64 + lane];
    bf16x8 b1 = Bp[(t * 2 + 1) * 64 + lane];
    acc0 = __builtin_amdgcn_mfma_f32_16x16x32_bf16(a, b0, acc0, 0, 0, 0);
    acc1 = __builtin_amdgcn_mfma_f32_16x16x32_bf16(a, b1, acc1, 0, 0, 0);
  }
#pragma unroll
  for (int nt = 0; nt < 2; ++nt){
    int col = nt * 16 + (lane & 15);
    if (col < 24){
      int r = col >> 3, isK = (col >> 2) & 1, h = col & 3;
      float* bp = isK ? kn : qn;
      f32x4 a = nt ? acc1 : acc0;
#pragma unroll
      for (int j = 0; j < 4; ++j){
        int row = row0 + quad * 4 + j;
        bp[((size_t)r * nN + row) * 4 + h] = a[j];
      }
    }
  }
}

// ---------------- MFMA GEMM: C[r] = A @ W[r], 128x256 pipeline, 2 blocks/CU ----
// (byte-for-byte the R6/round-1 verified version: 132us, 0 conflicts)
// Grid 2304: xcd=i&7, bm = xcd*32 + s/9, bnr=s%9 fastest (A-panel L2-hot).
// 8 waves (2Mx4N), wave tile 64x64, acc[4][4] (64 regs). LDS: 3 slabs of 24KB
// (A plane 8KB + B plane 16KB), BK=32. Slab row j holds rows 2j,2j+1,
// chunk-swizzled p = q^(j&7) (pre-swizzled global source, swizzled ds_read).
// One vmcnt(3) + one s_barrier per K-step; stage t+2 issued during phase t.
#define MM4(mi, av) \
    acc[mi][0] = __builtin_amdgcn_mfma_f32_16x16x32_bf16(av, b0, acc[mi][0], 0, 0, 0); \
    acc[mi][1] = __builtin_amdgcn_mfma_f32_16x16x32_bf16(av, b1, acc[mi][1], 0, 0, 0); \
    acc[mi][2] = __builtin_amdgcn_mfma_f32_16x16x32_bf16(av, b2, acc[mi][2], 0, 0, 0); \
    acc[mi][3] = __builtin_amdgcn_mfma_f32_16x16x32_bf16(av, b3, acc[mi][3], 0, 0, 0);

__global__ void __launch_bounds__(512, 4)
gemm_bf16(const unsigned short* __restrict__ A,
          const unsigned short* __restrict__ Bt,
          unsigned short* __restrict__ C, int M){
  __shared__ __align__(16) unsigned char lds[73728];   // 3 x (8KB A + 16KB B)
  const int K = DIM;
  int i = blockIdx.x;
  int xcd = i & 7, s = i >> 3;            // s in 0..287
  int bm  = xcd * 32 + s / 9;             // 0..255 (M/128 tiles)
  int bnr = s % 9;
  int rrel = bnr / 3, bn = bnr % 3;       // 3 N-tiles of 256
  int tid = threadIdx.x;
  int w = tid >> 6, lane = tid & 63;
  int wr = w >> 2, wc = w & 3;            // 2 x 4 wave grid, wave tile 64x64
  int m16 = lane & 15, quad = lane >> 4;

  // frag-read constants: plane row j = base + jlow, chunk p = q^(j&7)
  int jlow = m16 >> 1;
  int p    = (((m16 & 1) << 2) | quad) ^ jlow;
  int aoff = (wr * 32 + jlow) * 128 + p * 16;   // + mi*1024 within A plane (8KB)
  int boff = (wc * 32 + jlow) * 128 + p * 16;   // + ni*1024 within B plane (16KB)

  // stage constants: thread writes dest chunk p=tid&7 of plane row j=tid>>3,
  // which must hold logical chunk sq = p ^ (j&7)
  int sq  = (tid & 7) ^ ((tid >> 3) & 7);
  int rb  = 2 * (tid >> 3) + (sq >> 2);          // 0..127
  const unsigned short* gA  = A  + (size_t)(bm * 128 + rb) * K + (sq & 3) * 8;
  const unsigned short* gB0 = Bt + ((size_t)(rrel * DIM + bn * 256 + rb)) * K + (sq & 3) * 8;
  const unsigned short* gB1 = gB0 + (size_t)128 * K;   // rows 128..255 (same sq: 64%8==0)
  unsigned char* dst = &lds[w * 1024];           // wave-uniform; HW adds lane*16

  f32x4 acc[4][4];
#pragma unroll
  for (int a = 0; a < 4; ++a)
#pragma unroll
    for (int b = 0; b < 4; ++b) acc[a][b] = (f32x4){0.f, 0.f, 0.f, 0.f};

  auto STAGE = [&](int slot, int k0){
    unsigned char* base = dst + slot * 24576;
    gload16(gA  + k0, base);
    gload16(gB0 + k0, base + 8192);
    gload16(gB1 + k0, base + 16384);
  };
  auto LDA = [&](int slot, int mi) -> bf16x8 {
    return *(const bf16x8*)&lds[slot * 24576 + aoff + mi * 1024];
  };
  auto LDB = [&](int slot, int ni) -> bf16x8 {
    return *(const bf16x8*)&lds[slot * 24576 + 8192 + boff + ni * 1024];
  };
  auto PHASE = [&](int slotR, int k0, int slotW, int kW, bool doStage){
    bf16x8 b0 = LDB(slotR, 0), b1 = LDB(slotR, 1), b2 = LDB(slotR, 2), b3 = LDB(slotR, 3);
    bf16x8 a0 = LDA(slotR, 0), a1 = LDA(slotR, 1), a2 = LDA(slotR, 2), a3 = LDA(slotR, 3);
    if (doStage) STAGE(slotW, kW);
    __builtin_amdgcn_s_setprio(1);
    MM4(0, a0) MM4(1, a1) MM4(2, a2) MM4(3, a3)
    __builtin_amdgcn_s_setprio(0);
  };

  // prologue: KTILE 0 -> slot0, KTILE 1 -> slot1; wait slot0 (1 stays in flight)
  STAGE(0, 0); STAGE(1, 32);
  asm volatile("s_waitcnt vmcnt(3)");
  __builtin_amdgcn_s_barrier();

#pragma unroll 1
  for (int t = 0; t < 21; t += 3){          // K-steps 0..20
    int k0 = t * 32;
    PHASE(0, k0,       2, k0 + 64, true);
    asm volatile("s_waitcnt vmcnt(3)");
    __builtin_amdgcn_s_barrier();
    PHASE(1, k0 + 32,  0, k0 + 96, true);
    asm volatile("s_waitcnt vmcnt(3)");
    __builtin_amdgcn_s_barrier();
    PHASE(2, k0 + 64,  1, k0 + 128, true);
    asm volatile("s_waitcnt vmcnt(3)");
    __builtin_amdgcn_s_barrier();
  }
  PHASE(0, 672, 2, 736, true);              // K-step 21, stage 23 -> slot2
  asm volatile("s_waitcnt vmcnt(3)");
  __builtin_amdgcn_s_barrier();
  PHASE(1, 704, 0, 0, false);               // K-step 22
  asm volatile("s_waitcnt vmcnt(0)");
  __builtin_amdgcn_s_barrier();
  PHASE(2, 736, 0, 0, false);               // K-step 23

  unsigned short* Cg = C + ((size_t)rrel * M + (size_t)bm * 128) * DIM + bn * 256;
#pragma unroll
  for (int mi = 0; mi < 4; ++mi)
#pragma unroll
    for (int ni = 0; ni < 4; ++ni){
#pragma unroll
      for (int j = 0; j < 4; ++j){
        int row = wr * 64 + mi * 16 + quad * 4 + j;
        int col = wc * 64 + ni * 16 + m16;
        Cg[(size_t)row * DIM + col] = f2bf(acc[mi][ni][j]);
      }
    }
}

// ---------------- per-node attention + aggregation (one wave per node) ----------------
// Per-wave LDS for chunk payload/weights (no inner-loop shuffles); gathers
// batched 8-wide for MLP (24 independent loads in flight; avg deg 4.9 ->
// 94% of nodes finish in one iteration instead of 2 serial round-trips).
template<int H, bool ELU, bool OUT32>
__global__ void __launch_bounds__(256)
agg_kernel(const unsigned short* __restrict__ xr,
           const float* __restrict__ qn, const float* __restrict__ kn,
           const int* __restrict__ offs, const int* __restrict__ payload,
           const void* __restrict__ bias,
           void* __restrict__ outp,
           const int* __restrict__ flags, int nN, int E){
  const int WH = (H == 4) ? 4 : 1;
  __shared__ int   pay_s[4][64];
  __shared__ float w_s[4][64 * WH];
  int is32 = flags[0];
  int wv   = threadIdx.x >> 6;
  int lane = threadIdx.x & 63;
  int n = blockIdx.x * 4 + wv;
  int rs = offs[n], re = offs[n + 1];
  rs = max(rs, 0); re = min(re, E);
  const int myh = (H == 1) ? 0 : (lane >> 4);   // OUTC=192: lane*12/192 = lane/16

  float m_run[H], z_run[H], acc[12];
#pragma unroll
  for (int h = 0; h < H; ++h){ m_run[h] = -__builtin_inff(); z_run[h] = 0.f; }
#pragma unroll
  for (int i = 0; i < 12; ++i) acc[i] = 0.f;

  for (int base = rs; base < re; base += 64){
    int dc = min(64, re - base);
    int pay = 0;
    float al[H];
#pragma unroll
    for (int h = 0; h < H; ++h) al[h] = -__builtin_inff();
    if (lane < dc){
      pay = payload[base + lane];
      int et = pay >> 16, src = pay & 0xffff;
      if (H == 4){
        f32x4 qv = *(const f32x4*)(qn + ((size_t)et * nN + n)   * 4);
        f32x4 kv = *(const f32x4*)(kn + ((size_t)et * nN + src) * 4);
#pragma unroll
        for (int h = 0; h < H; ++h){
          float a = qv[h & 3] + kv[h & 3];
          al[h] = (a > 0.f) ? a : 0.2f * a;
        }
      } else {
        float a = qn[((size_t)et * nN + n) * 4] + kn[((size_t)et * nN + src) * 4];
        al[0] = (a > 0.f) ? a : 0.2f * a;
      }
    }
    // online-softmax chunk update
    float scs[H], wgt[H];
#pragma unroll
    for (int h = 0; h < H; ++h){
      float v = al[h];
      for (int off = 32; off; off >>= 1) v = fmaxf(v, __shfl_xor(v, off));
      float nm = fmaxf(m_run[h], v);
      scs[h] = (m_run[h] == -__builtin_inff()) ? 0.f : expf(m_run[h] - nm);
      m_run[h] = nm;
      wgt[h] = (lane < dc) ? expf(al[h] - nm) : 0.f;
      float s = wgt[h];
      for (int off = 32; off; off >>= 1) s += __shfl_xor(s, off);
      z_run[h] = z_run[h] * scs[h] + s;
    }
    float msc = sel<H>(scs, myh);
#pragma unroll
    for (int i = 0; i < 12; ++i) acc[i] *= msc;

    // stash chunk data in per-wave LDS (same-wave DS ops are in-order)
    if (lane < dc){
      pay_s[wv][lane] = pay;
#pragma unroll
      for (int h = 0; h < WH; ++h) w_s[wv][lane * WH + h] = wgt[h];
    }

    // batched gather-accumulate: 8 edges -> 24 loads in flight
    for (int j0 = 0; j0 < dc; j0 += 8){
      uint2 c[8][3];
      float w8[8];
#pragma unroll
      for (int u = 0; u < 8; ++u){
        int jc = j0 + u;
        int ok = jc < dc;
        int jl = ok ? jc : j0;
        int pj = pay_s[wv][jl];
        float ww = w_s[wv][jl * WH + ((H == 1) ? 0 : myh)];
        w8[u] = ok ? ww : 0.f;
        int et = pj >> 16, src = pj & 0xffff;
        const uint2* rp = (const uint2*)(xr + ((size_t)et * nN + src) * DIM + lane * 12);
        c[u][0] = rp[0]; c[u][1] = rp[1]; c[u][2] = rp[2];
      }
#pragma unroll
      for (int u = 0; u < 8; ++u){
        float wj = w8[u];
        acc[0]  += wj * bfl(c[u][0].x); acc[1]  += wj * bfh(c[u][0].x);
        acc[2]  += wj * bfl(c[u][0].y); acc[3]  += wj * bfh(c[u][0].y);
        acc[4]  += wj * bfl(c[u][1].x); acc[5]  += wj * bfh(c[u][1].x);
        acc[6]  += wj * bfl(c[u][1].y); acc[7]  += wj * bfh(c[u][1].y);
        acc[8]  += wj * bfl(c[u][2].x); acc[9]  += wj * bfh(c[u][2].x);
        acc[10] += wj * bfl(c[u][2].y); acc[11] += wj * bfh(c[u][2].y);
      }
    }
  }

  float inv = 1.0f / (sel<H>(z_run, myh) + 1e-16f);
  float o[12];
#pragma unroll
  for (int i = 0; i < 12; ++i){
    float v = acc[i] * inv + ldf(bias, (size_t)lane * 12 + i, is32);
    if (ELU) v = (v > 0.f) ? v : (expf(v) - 1.f);
    o[i] = v;
  }
  if (OUT32 && is32){
    float* op = (float*)outp + (size_t)n * DIM + lane * 12;
    float4 f0 = {o[0], o[1], o[2],  o[3]};
    float4 f1 = {o[4], o[5], o[6],  o[7]};
    float4 f2 = {o[8], o[9], o[10], o[11]};
    ((float4*)op)[0] = f0; ((float4*)op)[1] = f1; ((float4*)op)[2] = f2;
  } else {
    uint2* op = (uint2*)((unsigned short*)outp + (size_t)n * DIM + lane * 12);
    uint2 s0, s1, s2;
    s0.x = pck(o[0], o[1]);  s0.y = pck(o[2], o[3]);
    s1.x = pck(o[4], o[5]);  s1.y = pck(o[6], o[7]);
    s2.x = pck(o[8], o[9]);  s2.y = pck(o[10], o[11]);
    op[0] = s0; op[1] = s1; op[2] = s2;
  }
}

// ---------------- launcher ----------------
extern "C" void kernel_launch(void* const* d_in, const int* in_sizes, int n_in,
                              void* d_out, int out_size, void* d_ws, size_t ws_size,
                              hipStream_t stream){
  const void* x   = d_in[0];
  const void* ei  = d_in[1];
  const void* ety = d_in[2];
  const void* W1  = d_in[3];
  const void* q1  = d_in[4];
  const void* k1  = d_in[5];
  const void* b1  = d_in[6];
  const void* W2  = d_in[7];
  const void* q2  = d_in[8];
  const void* k2  = d_in[9];
  const void* b2  = d_in[10];

  int nN = in_sizes[0] / DIM;   // 32768
  int E  = in_sizes[2];         // 160000

  char* ws = (char*)d_ws;
  size_t off = 0;
  auto alloc = [&](size_t bytes) -> void* {
    void* p = ws + off;
    off += (bytes + 255) & ~(size_t)255;
    return p;
  };
  unsigned short* xr   = (unsigned short*)alloc((size_t)NREL * nN * DIM * 2);
  unsigned short* xb   = (unsigned short*)alloc((size_t)nN * DIM * 2);
  unsigned short* h    = (unsigned short*)alloc((size_t)nN * DIM * 2);
  unsigned short* Wt   = (unsigned short*)alloc((size_t)NREL * DIM * DIM * 2);
  unsigned short* Wqkb = (unsigned short*)alloc((size_t)DIM * 32 * 2);
  unsigned short* Bpk  = (unsigned short*)alloc((size_t)3072 * 16);
  float* qn  = (float*)alloc((size_t)NREL * nN * 4 * 4);
  float* kn  = (float*)alloc((size_t)NREL * nN * 4 * 4);
  int* offs    = (int*)alloc((size_t)(nN + 1) * 4);
  int* cursor  = (int*)alloc((size_t)nN * 4);
  int* counts  = (int*)alloc((size_t)nN * 4);
  int* payload = (int*)alloc((size_t)E * 4);
  int* flags   = (int*)alloc(16);

  detect_kernel<<<1, 256, 0, stream>>>((const unsigned short*)x, (const unsigned*)ei,
                                       (const unsigned*)ety, flags);
  convert_x<<<(nN * DIM / 4 + 255) / 256, 256, 0, stream>>>(x, xb, flags, nN * DIM / 4);

  hipMemsetAsync(counts, 0, (size_t)nN * 4, stream);
  hist_kernel<<<(E + 255) / 256, 256, 0, stream>>>(ei, counts, flags, E);
  scan_kernel<<<1, 1024, 0, stream>>>(counts, offs, cursor, nN);
  scatter_kernel<<<(E + 255) / 256, 256, 0, stream>>>(ei, ety, cursor, payload, flags, E);

  dim3 tg(DIM / 32, DIM / 32, NREL), tb(32, 8);
  int gemm_blocks = 8 * (32 * 9);   // 2304: 256 m-tiles x 9 (r,bn)

  // ---- layer 1 (H=4, ELU) ----
  transpose_w<<<tg, tb, 0, stream>>>(W1, Wt, flags);
  hipMemsetAsync(Wqkb, 0, (size_t)DIM * 32 * 2, stream);
  wqk_kernel<4><<<(NREL * DIM) / 4, 256, 0, stream>>>(W1, q1, k1, Wqkb, flags);
  pack_b<<<12, 256, 0, stream>>>(Wqkb, Bpk);
  qnkn_mfma<<<nN / 64, 256, 0, stream>>>(xb, Bpk, qn, kn, nN);
  gemm_bf16<<<gemm_blocks, 512, 0, stream>>>(xb, Wt, xr, nN);
  agg_kernel<4, true, false><<<nN / 4, 256, 0, stream>>>(xr, qn, kn, offs, payload, b1, h,
                                                         flags, nN, E);

  // ---- layer 2 (H=1, no activation) ----
  transpose_w<<<tg, tb, 0, stream>>>(W2, Wt, flags);
  hipMemsetAsync(Wqkb, 0, (size_t)DIM * 32 * 2, stream);
  wqk_kernel<1><<<(NREL * DIM) / 4, 256, 0, stream>>>(W2, q2, k2, Wqkb, flags);
  pack_b<<<12, 256, 0, stream>>>(Wqkb, Bpk);
  qnkn_mfma<<<nN / 64, 256, 0, stream>>>(h, Bpk, qn, kn, nN);
  gemm_bf16<<<gemm_blocks, 512, 0, stream>>>(h, Wt, xr, nN);
  agg_kernel<1, false, true><<<nN / 4, 256, 0, stream>>>(xr, qn, kn, offs, payload, b2,
                                                         d_out, flags, nN, E);
}

// Round 9
// 651.441 us; speedup vs baseline: 1.1018x; 1.0372x over previous
//
#include <hip/hip_runtime.h>

// RGAT encoder, 2 layers. N=32768, E=160000, DIM=768, R=3, heads 4 then 1.
// Round 13: RESUBMIT of round 12 (infra failure: "MI355X container failed
// twice" -- no pytest/profile output; kernel never judged. Audit found no
// OOB/deadlock: gather indices max 767 in-row, hq[q] exact since 192=48*4,
// no new sync). Theory unchanged:
//  - gemm: byte-identical banked 132us version (0 conflicts, Occ 40%)
//  - agg single change: lane->column remap from [12*lane..+12) stride-24B
//    to {q*256 + 4*lane | q=0,1,2} contiguous 512B blocks per gather instr
//    -> 24 line-transactions/edge vs 72 (3x fewer). Per-chunk head
//    hq[q] = (q*64+lane)/48 for weight/rescale/normalize/bias/store.

#define DIM   768
#define NREL  3

typedef __bf16 bf16x8 __attribute__((ext_vector_type(8)));
typedef float  f32x4  __attribute__((ext_vector_type(4)));
typedef unsigned short us4 __attribute__((ext_vector_type(4)));
typedef unsigned short us8 __attribute__((ext_vector_type(8)));

// ---------------- helpers ----------------
__device__ __forceinline__ float bfs(unsigned short u){
  union { unsigned u; float f; } v; v.u = ((unsigned)u) << 16; return v.f;
}
__device__ __forceinline__ float bfl(unsigned x){
  union { unsigned u; float f; } v; v.u = x << 16; return v.f;
}
__device__ __forceinline__ float bfh(unsigned x){
  union { unsigned u; float f; } v; v.u = x & 0xffff0000u; return v.f;
}
__device__ __forceinline__ unsigned short f2bf(float f){   // RNE
  union { float f; unsigned u; } v; v.f = f;
  unsigned r = v.u + 0x7fffu + ((v.u >> 16) & 1u);
  return (unsigned short)(r >> 16);
}
__device__ __forceinline__ unsigned pck(float a, float b){
  return (unsigned)f2bf(a) | ((unsigned)f2bf(b) << 16);
}
__device__ __forceinline__ float ldf(const void* p, size_t i, int is32){
  return is32 ? ((const float*)p)[i] : bfs(((const unsigned short*)p)[i]);
}
__device__ __forceinline__ int ldi(const void* p, size_t i, int is64){
  return is64 ? ((const int*)p)[2 * i] : ((const int*)p)[i];
}

typedef __attribute__((address_space(1))) void gvoid_t;
typedef __attribute__((address_space(3))) void lvoid_t;
__device__ __forceinline__ void gload16(const void* g, void* l){
  __builtin_amdgcn_global_load_lds((gvoid_t*)g, (lvoid_t*)l, 16, 0, 0);
}

template<int H>
__device__ __forceinline__ float sel(const float (&a)[H], int h){
  float v = a[0];
#pragma unroll
  for (int i = 1; i < H; ++i) v = (h == i) ? a[i] : v;
  return v;
}

// ---------------- dtype detection ----------------
__global__ void detect_kernel(const unsigned short* __restrict__ xu,
                              const unsigned* __restrict__ eiu,
                              const unsigned* __restrict__ etyu,
                              int* __restrict__ flags){
  __shared__ int s_weird, s_ei, s_ety;
  int t = threadIdx.x;
  if (t == 0){ s_weird = 0; s_ei = 0; s_ety = 0; }
  __syncthreads();
  unsigned short u = xu[2 * t];
  int ex = (u >> 7) & 0xff;
  if (ex >= 0xF0 || ex <= 0x40) atomicAdd(&s_weird, 1);
  if (t < 128){
    if (eiu[2 * t + 1]  != 0) atomicAdd(&s_ei, 1);
    if (etyu[2 * t + 1] != 0) atomicAdd(&s_ety, 1);
  }
  __syncthreads();
  if (t == 0){
    flags[0] = (s_weird > 16) ? 1 : 0;
    flags[1] = (s_ei  == 0) ? 1 : 0;
    flags[2] = (s_ety == 0) ? 1 : 0;
  }
}

// ---------------- x -> internal bf16 ----------------
__global__ void convert_x(const void* __restrict__ xin, unsigned short* __restrict__ xb,
                          const int* __restrict__ flags, int n4){
  int i = blockIdx.x * blockDim.x + threadIdx.x;
  if (i >= n4) return;
  if (flags[0]){
    float4 v = ((const float4*)xin)[i];
    us4 o; o.x = f2bf(v.x); o.y = f2bf(v.y); o.z = f2bf(v.z); o.w = f2bf(v.w);
    ((us4*)xb)[i] = o;
  } else {
    ((us4*)xb)[i] = ((const us4*)xin)[i];
  }
}

// ---------------- CSR build ----------------
__global__ void hist_kernel(const void* __restrict__ ei, int* __restrict__ counts,
                            const int* __restrict__ flags, int E){
  int e = blockIdx.x * blockDim.x + threadIdx.x;
  if (e < E) atomicAdd(&counts[ldi(ei, (size_t)E + e, flags[1])], 1);
}

__global__ void scan_kernel(const int* __restrict__ counts, int* __restrict__ offs,
                            int* __restrict__ cursor, int n){
  __shared__ int s[1024];
  int tid = threadIdx.x;
  int base = tid * 32;
  int loc[32];
  int run = 0;
#pragma unroll
  for (int i = 0; i < 32; ++i){ loc[i] = run; run += counts[base + i]; }
  s[tid] = run;
  __syncthreads();
  for (int off = 1; off < 1024; off <<= 1){
    int add = (tid >= off) ? s[tid - off] : 0;
    __syncthreads();
    s[tid] += add;
    __syncthreads();
  }
  int ex = (tid == 0) ? 0 : s[tid - 1];
#pragma unroll
  for (int i = 0; i < 32; ++i){
    int o = ex + loc[i];
    offs[base + i]   = o;
    cursor[base + i] = o;
  }
  if (tid == 1023) offs[n] = s[1023];
}

__global__ void scatter_kernel(const void* __restrict__ ei, const void* __restrict__ ety,
                               int* __restrict__ cursor, int* __restrict__ payload,
                               const int* __restrict__ flags, int E){
  int e = blockIdx.x * blockDim.x + threadIdx.x;
  if (e < E){
    int dst = ldi(ei, (size_t)E + e, flags[1]);
    int src = ldi(ei, (size_t)e,     flags[1]);
    int et  = ldi(ety, (size_t)e,    flags[2]);
    int pos = atomicAdd(&cursor[dst], 1);
    payload[pos] = (et << 16) | src;
  }
}

// ---------------- W transpose+convert ----------------
__global__ void transpose_w(const void* __restrict__ W, unsigned short* __restrict__ Wt,
                            const int* __restrict__ flags){
  __shared__ unsigned short t[32][33];
  int is32 = flags[0];
  int r = blockIdx.z;
  size_t Wb = (size_t)r * DIM * DIM;
  unsigned short* Wd = Wt + (size_t)r * DIM * DIM;
  int tx = threadIdx.x, ty = threadIdx.y;
  int x  = blockIdx.x * 32 + tx;
  int y0 = blockIdx.y * 32;
#pragma unroll
  for (int i = 0; i < 32; i += 8)
    t[ty + i][tx] = f2bf(ldf(W, Wb + (size_t)(y0 + ty + i) * DIM + x, is32));
  __syncthreads();
  int x2 = blockIdx.y * 32 + tx;
  int y2 = blockIdx.x * 32;
#pragma unroll
  for (int i = 0; i < 32; i += 8) Wd[(size_t)(y2 + ty + i) * DIM + x2] = t[tx][ty + i];
}

// ---------------- Wqkb[d][32] (bf16) = [W@q | W@k] per relation ----------------
// col = r*8 + isK*4 + h  (cols 24..31 pad; zeroed by memset before launch)
template<int H>
__global__ void wqk_kernel(const void* __restrict__ W,
                           const void* __restrict__ q, const void* __restrict__ k,
                           unsigned short* __restrict__ Wqkb,
                           const int* __restrict__ flags){
  int is32 = flags[0];
  int wid  = (blockIdx.x * blockDim.x + threadIdx.x) >> 6;
  int lane = threadIdx.x & 63;
  int r = wid / DIM, d = wid % DIM;
  size_t Wrow = ((size_t)r * DIM + d) * DIM;
  float aq[H], ak[H];
#pragma unroll
  for (int h = 0; h < H; ++h){ aq[h] = 0.f; ak[h] = 0.f; }
#pragma unroll
  for (int j = 0; j < 12; ++j){
    int f = j * 64 + lane;
    float wv = ldf(W, Wrow + f, is32);
#pragma unroll
    for (int h = 0; h < H; ++h){
      aq[h] += wv * ldf(q, (size_t)f * H + h, is32);
      ak[h] += wv * ldf(k, (size_t)f * H + h, is32);
    }
  }
#pragma unroll
  for (int h = 0; h < H; ++h){
    for (int off = 32; off; off >>= 1){
      aq[h] += __shfl_xor(aq[h], off);
      ak[h] += __shfl_xor(ak[h], off);
    }
  }
  if (lane == 0){
#pragma unroll
    for (int h = 0; h < H; ++h){
      Wqkb[(size_t)d * 32 + r * 8 + h]     = f2bf(aq[h]);
      Wqkb[(size_t)d * 32 + r * 8 + 4 + h] = f2bf(ak[h]);
    }
  }
}

// ---------------- pack Wqkb into MFMA B-fragment order ----------------
// Bpk[t][nt][lane] = 8 bf16: Wqkb[t*32 + (lane>>4)*8 + j][nt*16 + (lane&15)]
__global__ void pack_b(const unsigned short* __restrict__ Wqkb, unsigned short* __restrict__ Bpk){
  int i = blockIdx.x * 256 + threadIdx.x;   // 24*2*64 = 3072
  if (i >= 3072) return;
  int lane = i & 63, nt = (i >> 6) & 1, t = i >> 7;
  int kb = t * 32 + (lane >> 4) * 8;
  int col = nt * 16 + (lane & 15);
  us8 v;
#pragma unroll
  for (int j = 0; j < 8; ++j) v[j] = Wqkb[(size_t)(kb + j) * 32 + col];
  ((us8*)Bpk)[i] = v;
}

// ---------------- qn/kn via skinny MFMA: [N,768]@[768,32] ----------------
// output layout qn[r][n][4], kn[r][n][4] fp32 (H=4 uses all, H=1 uses h=0)
__global__ void __launch_bounds__(256)
qnkn_mfma(const unsigned short* __restrict__ X, const unsigned short* __restrict__ Bpk,
          float* __restrict__ qn, float* __restrict__ kn, int nN){
  int wv = threadIdx.x >> 6, lane = threadIdx.x & 63;
  int row0 = (blockIdx.x * 4 + wv) * 16;
  int ar = lane & 15, quad = lane >> 4;
  const unsigned short* Arow = X + (size_t)(row0 + ar) * DIM + quad * 8;
  const bf16x8* Bp = (const bf16x8*)Bpk;
  f32x4 acc0 = {0.f,0.f,0.f,0.f}, acc1 = {0.f,0.f,0.f,0.f};
#pragma unroll
  for (int t = 0; t < 24; ++t){
    bf16x8 a  = *(const bf16x8*)(Arow + t * 32);
    bf16x8 b0 = Bp[(t * 2 + 0) * 64 + lane];
    bf16x8 b1 = Bp[(t * 2 + 1) * 64 + lane];
    acc0 = __builtin_amdgcn_mfma_f32_16x16x32_bf16(a, b0, acc0, 0, 0, 0);
    acc1 = __builtin_amdgcn_mfma_f32_16x16x32_bf16(a, b1, acc1, 0, 0, 0);
  }
#pragma unroll
  for (int nt = 0; nt < 2; ++nt){
    int col = nt * 16 + (lane & 15);
    if (col < 24){
      int r = col >> 3, isK = (col >> 2) & 1, h = col & 3;
      float* bp = isK ? kn : qn;
      f32x4 a = nt ? acc1 : acc0;
#pragma unroll
      for (int j = 0; j < 4; ++j){
        int row = row0 + quad * 4 + j;
        bp[((size_t)r * nN + row) * 4 + h] = a[j];
      }
    }
  }
}

// ---------------- MFMA GEMM: C[r] = A @ W[r], 128x256 pipeline, 2 blocks/CU ----
// (byte-for-byte the verified version: 132us, 0 conflicts, Occ 40%)
// Grid 2304: xcd=i&7, bm = xcd*32 + s/9, bnr=s%9 fastest (A-panel L2-hot).
// 8 waves (2Mx4N), wave tile 64x64, acc[4][4] (64 regs). LDS: 3 slabs of 24KB
// (A plane 8KB + B plane 16KB), BK=32. Slab row j holds rows 2j,2j+1,
// chunk-swizzled p = q^(j&7) (pre-swizzled global source, swizzled ds_read).
// One vmcnt(3) + one s_barrier per K-step; stage t+2 issued during phase t.
#define MM4(mi, av) \
    acc[mi][0] = __builtin_amdgcn_mfma_f32_16x16x32_bf16(av, b0, acc[mi][0], 0, 0, 0); \
    acc[mi][1] = __builtin_amdgcn_mfma_f32_16x16x32_bf16(av, b1, acc[mi][1], 0, 0, 0); \
    acc[mi][2] = __builtin_amdgcn_mfma_f32_16x16x32_bf16(av, b2, acc[mi][2], 0, 0, 0); \
    acc[mi][3] = __builtin_amdgcn_mfma_f32_16x16x32_bf16(av, b3, acc[mi][3], 0, 0, 0);

__global__ void __launch_bounds__(512, 4)
gemm_bf16(const unsigned short* __restrict__ A,
          const unsigned short* __restrict__ Bt,
          unsigned short* __restrict__ C, int M){
  __shared__ __align__(16) unsigned char lds[73728];   // 3 x (8KB A + 16KB B)
  const int K = DIM;
  int i = blockIdx.x;
  int xcd = i & 7, s = i >> 3;            // s in 0..287
  int bm  = xcd * 32 + s / 9;             // 0..255 (M/128 tiles)
  int bnr = s % 9;
  int rrel = bnr / 3, bn = bnr % 3;       // 3 N-tiles of 256
  int tid = threadIdx.x;
  int w = tid >> 6, lane = tid & 63;
  int wr = w >> 2, wc = w & 3;            // 2 x 4 wave grid, wave tile 64x64
  int m16 = lane & 15, quad = lane >> 4;

  // frag-read constants: plane row j = base + jlow, chunk p = q^(j&7)
  int jlow = m16 >> 1;
  int p    = (((m16 & 1) << 2) | quad) ^ jlow;
  int aoff = (wr * 32 + jlow) * 128 + p * 16;   // + mi*1024 within A plane (8KB)
  int boff = (wc * 32 + jlow) * 128 + p * 16;   // + ni*1024 within B plane (16KB)

  // stage constants: thread writes dest chunk p=tid&7 of plane row j=tid>>3,
  // which must hold logical chunk sq = p ^ (j&7)
  int sq  = (tid & 7) ^ ((tid >> 3) & 7);
  int rb  = 2 * (tid >> 3) + (sq >> 2);          // 0..127
  const unsigned short* gA  = A  + (size_t)(bm * 128 + rb) * K + (sq & 3) * 8;
  const unsigned short* gB0 = Bt + ((size_t)(rrel * DIM + bn * 256 + rb)) * K + (sq & 3) * 8;
  const unsigned short* gB1 = gB0 + (size_t)128 * K;   // rows 128..255 (same sq: 64%8==0)
  unsigned char* dst = &lds[w * 1024];           // wave-uniform; HW adds lane*16

  f32x4 acc[4][4];
#pragma unroll
  for (int a = 0; a < 4; ++a)
#pragma unroll
    for (int b = 0; b < 4; ++b) acc[a][b] = (f32x4){0.f, 0.f, 0.f, 0.f};

  auto STAGE = [&](int slot, int k0){
    unsigned char* base = dst + slot * 24576;
    gload16(gA  + k0, base);
    gload16(gB0 + k0, base + 8192);
    gload16(gB1 + k0, base + 16384);
  };
  auto LDA = [&](int slot, int mi) -> bf16x8 {
    return *(const bf16x8*)&lds[slot * 24576 + aoff + mi * 1024];
  };
  auto LDB = [&](int slot, int ni) -> bf16x8 {
    return *(const bf16x8*)&lds[slot * 24576 + 8192 + boff + ni * 1024];
  };
  auto PHASE = [&](int slotR, int k0, int slotW, int kW, bool doStage){
    bf16x8 b0 = LDB(slotR, 0), b1 = LDB(slotR, 1), b2 = LDB(slotR, 2), b3 = LDB(slotR, 3);
    bf16x8 a0 = LDA(slotR, 0), a1 = LDA(slotR, 1), a2 = LDA(slotR, 2), a3 = LDA(slotR, 3);
    if (doStage) STAGE(slotW, kW);
    __builtin_amdgcn_s_setprio(1);
    MM4(0, a0) MM4(1, a1) MM4(2, a2) MM4(3, a3)
    __builtin_amdgcn_s_setprio(0);
  };

  // prologue: KTILE 0 -> slot0, KTILE 1 -> slot1; wait slot0 (1 stays in flight)
  STAGE(0, 0); STAGE(1, 32);
  asm volatile("s_waitcnt vmcnt(3)");
  __builtin_amdgcn_s_barrier();

#pragma unroll 1
  for (int t = 0; t < 21; t += 3){          // K-steps 0..20
    int k0 = t * 32;
    PHASE(0, k0,       2, k0 + 64, true);
    asm volatile("s_waitcnt vmcnt(3)");
    __builtin_amdgcn_s_barrier();
    PHASE(1, k0 + 32,  0, k0 + 96, true);
    asm volatile("s_waitcnt vmcnt(3)");
    __builtin_amdgcn_s_barrier();
    PHASE(2, k0 + 64,  1, k0 + 128, true);
    asm volatile("s_waitcnt vmcnt(3)");
    __builtin_amdgcn_s_barrier();
  }
  PHASE(0, 672, 2, 736, true);              // K-step 21, stage 23 -> slot2
  asm volatile("s_waitcnt vmcnt(3)");
  __builtin_amdgcn_s_barrier();
  PHASE(1, 704, 0, 0, false);               // K-step 22
  asm volatile("s_waitcnt vmcnt(0)");
  __builtin_amdgcn_s_barrier();
  PHASE(2, 736, 0, 0, false);               // K-step 23

  unsigned short* Cg = C + ((size_t)rrel * M + (size_t)bm * 128) * DIM + bn * 256;
#pragma unroll
  for (int mi = 0; mi < 4; ++mi)
#pragma unroll
    for (int ni = 0; ni < 4; ++ni){
#pragma unroll
      for (int j = 0; j < 4; ++j){
        int row = wr * 64 + mi * 16 + quad * 4 + j;
        int col = wc * 64 + ni * 16 + m16;
        Cg[(size_t)row * DIM + col] = f2bf(acc[mi][ni][j]);
      }
    }
}

// ---------------- per-node attention + aggregation (one wave per node) ----------------
// Lane owns 3 column-chunks {q*256 + 4*lane .. +3}: each gather instruction
// reads a contiguous aligned 512B block of the source row (every 64B line
// touched exactly once -> 24 line-transactions/edge vs 72 for the old
// stride-24B layout). Chunk q's head hq[q] = (q*64+lane)/48 (4-col chunks
// never straddle a head boundary since 192 = 48*4).
template<int H, bool ELU, bool OUT32>
__global__ void __launch_bounds__(256)
agg_kernel(const unsigned short* __restrict__ xr,
           const float* __restrict__ qn, const float* __restrict__ kn,
           const int* __restrict__ offs, const int* __restrict__ payload,
           const void* __restrict__ bias,
           void* __restrict__ outp,
           const int* __restrict__ flags, int nN, int E){
  const int WH = (H == 4) ? 4 : 1;
  __shared__ int   pay_s[4][64];
  __shared__ float w_s[4][64 * WH];
  int is32 = flags[0];
  int wv   = threadIdx.x >> 6;
  int lane = threadIdx.x & 63;
  int n = blockIdx.x * 4 + wv;
  int rs = offs[n], re = offs[n + 1];
  rs = max(rs, 0); re = min(re, E);
  int hq[3];
#pragma unroll
  for (int q = 0; q < 3; ++q) hq[q] = (H == 1) ? 0 : ((q * 64 + lane) / 48);

  float m_run[H], z_run[H], acc[12];
#pragma unroll
  for (int h = 0; h < H; ++h){ m_run[h] = -__builtin_inff(); z_run[h] = 0.f; }
#pragma unroll
  for (int i = 0; i < 12; ++i) acc[i] = 0.f;

  for (int base = rs; base < re; base += 64){
    int dc = min(64, re - base);
    int pay = 0;
    float al[H];
#pragma unroll
    for (int h = 0; h < H; ++h) al[h] = -__builtin_inff();
    if (lane < dc){
      pay = payload[base + lane];
      int et = pay >> 16, src = pay & 0xffff;
      if (H == 4){
        f32x4 qv = *(const f32x4*)(qn + ((size_t)et * nN + n)   * 4);
        f32x4 kv = *(const f32x4*)(kn + ((size_t)et * nN + src) * 4);
#pragma unroll
        for (int h = 0; h < H; ++h){
          float a = qv[h & 3] + kv[h & 3];
          al[h] = (a > 0.f) ? a : 0.2f * a;
        }
      } else {
        float a = qn[((size_t)et * nN + n) * 4] + kn[((size_t)et * nN + src) * 4];
        al[0] = (a > 0.f) ? a : 0.2f * a;
      }
    }
    // online-softmax chunk update
    float scs[H], wgt[H];
#pragma unroll
    for (int h = 0; h < H; ++h){
      float v = al[h];
      for (int off = 32; off; off >>= 1) v = fmaxf(v, __shfl_xor(v, off));
      float nm = fmaxf(m_run[h], v);
      scs[h] = (m_run[h] == -__builtin_inff()) ? 0.f : expf(m_run[h] - nm);
      m_run[h] = nm;
      wgt[h] = (lane < dc) ? expf(al[h] - nm) : 0.f;
      float s = wgt[h];
      for (int off = 32; off; off >>= 1) s += __shfl_xor(s, off);
      z_run[h] = z_run[h] * scs[h] + s;
    }
#pragma unroll
    for (int q = 0; q < 3; ++q){
      float msc = sel<H>(scs, hq[q]);
#pragma unroll
      for (int j = 0; j < 4; ++j) acc[q * 4 + j] *= msc;
    }

    // stash chunk data in per-wave LDS (same-wave DS ops are in-order)
    if (lane < dc){
      pay_s[wv][lane] = pay;
#pragma unroll
      for (int h = 0; h < WH; ++h) w_s[wv][lane * WH + h] = wgt[h];
    }

    // batched gather-accumulate: 4 edges -> 12 contiguous-block loads in flight
    for (int j0 = 0; j0 < dc; j0 += 4){
      uint2 c[4][3];
      float w43[4][3];
#pragma unroll
      for (int u = 0; u < 4; ++u){
        int jc = j0 + u;
        int ok = jc < dc;
        int jl = ok ? jc : j0;
        int pj = pay_s[wv][jl];
#pragma unroll
        for (int q = 0; q < 3; ++q){
          float ww = w_s[wv][jl * WH + ((H == 1) ? 0 : hq[q])];
          w43[u][q] = ok ? ww : 0.f;
        }
        int et = pj >> 16, src = pj & 0xffff;
        const uint2* rp = (const uint2*)(xr + ((size_t)et * nN + src) * DIM) + lane;
        c[u][0] = rp[0]; c[u][1] = rp[64]; c[u][2] = rp[128];
      }
#pragma unroll
      for (int u = 0; u < 4; ++u){
#pragma unroll
        for (int q = 0; q < 3; ++q){
          float wj = w43[u][q];
          acc[q * 4 + 0] += wj * bfl(c[u][q].x);
          acc[q * 4 + 1] += wj * bfh(c[u][q].x);
          acc[q * 4 + 2] += wj * bfl(c[u][q].y);
          acc[q * 4 + 3] += wj * bfh(c[u][q].y);
        }
      }
    }
  }

  float o[12];
#pragma unroll
  for (int q = 0; q < 3; ++q){
    float inv = 1.0f / (sel<H>(z_run, hq[q]) + 1e-16f);
#pragma unroll
    for (int j = 0; j < 4; ++j){
      float v = acc[q * 4 + j] * inv + ldf(bias, (size_t)(q * 256 + lane * 4 + j), is32);
      if (ELU) v = (v > 0.f) ? v : (expf(v) - 1.f);
      o[q * 4 + j] = v;
    }
  }
  if (OUT32 && is32){
    float* op = (float*)outp + (size_t)n * DIM + lane * 4;
    ((float4*)(op      ))[0] = (float4){o[0], o[1], o[2],  o[3]};
    ((float4*)(op + 256))[0] = (float4){o[4], o[5], o[6],  o[7]};
    ((float4*)(op + 512))[0] = (float4){o[8], o[9], o[10], o[11]};
  } else {
    unsigned short* ob = (unsigned short*)outp + (size_t)n * DIM + lane * 4;
    uint2 s0, s1, s2;
    s0.x = pck(o[0], o[1]);  s0.y = pck(o[2],  o[3]);
    s1.x = pck(o[4], o[5]);  s1.y = pck(o[6],  o[7]);
    s2.x = pck(o[8], o[9]);  s2.y = pck(o[10], o[11]);
    *(uint2*)(ob      ) = s0;
    *(uint2*)(ob + 256) = s1;
    *(uint2*)(ob + 512) = s2;
  }
}

// ---------------- launcher ----------------
extern "C" void kernel_launch(void* const* d_in, const int* in_sizes, int n_in,
                              void* d_out, int out_size, void* d_ws, size_t ws_size,
                              hipStream_t stream){
  const void* x   = d_in[0];
  const void* ei  = d_in[1];
  const void* ety = d_in[2];
  const void* W1  = d_in[3];
  const void* q1  = d_in[4];
  const void* k1  = d_in[5];
  const void* b1  = d_in[6];
  const void* W2  = d_in[7];
  const void* q2  = d_in[8];
  const void* k2  = d_in[9];
  const void* b2  = d_in[10];

  int nN = in_sizes[0] / DIM;   // 32768
  int E  = in_sizes[2];         // 160000

  char* ws = (char*)d_ws;
  size_t off = 0;
  auto alloc = [&](size_t bytes) -> void* {
    void* p = ws + off;
    off += (bytes + 255) & ~(size_t)255;
    return p;
  };
  unsigned short* xr   = (unsigned short*)alloc((size_t)NREL * nN * DIM * 2);
  unsigned short* xb   = (unsigned short*)alloc((size_t)nN * DIM * 2);
  unsigned short* h    = (unsigned short*)alloc((size_t)nN * DIM * 2);
  unsigned short* Wt   = (unsigned short*)alloc((size_t)NREL * DIM * DIM * 2);
  unsigned short* Wqkb = (unsigned short*)alloc((size_t)DIM * 32 * 2);
  unsigned short* Bpk  = (unsigned short*)alloc((size_t)3072 * 16);
  float* qn  = (float*)alloc((size_t)NREL * nN * 4 * 4);
  float* kn  = (float*)alloc((size_t)NREL * nN * 4 * 4);
  int* offs    = (int*)alloc((size_t)(nN + 1) * 4);
  int* cursor  = (int*)alloc((size_t)nN * 4);
  int* counts  = (int*)alloc((size_t)nN * 4);
  int* payload = (int*)alloc((size_t)E * 4);
  int* flags   = (int*)alloc(16);

  detect_kernel<<<1, 256, 0, stream>>>((const unsigned short*)x, (const unsigned*)ei,
                                       (const unsigned*)ety, flags);
  convert_x<<<(nN * DIM / 4 + 255) / 256, 256, 0, stream>>>(x, xb, flags, nN * DIM / 4);

  hipMemsetAsync(counts, 0, (size_t)nN * 4, stream);
  hist_kernel<<<(E + 255) / 256, 256, 0, stream>>>(ei, counts, flags, E);
  scan_kernel<<<1, 1024, 0, stream>>>(counts, offs, cursor, nN);
  scatter_kernel<<<(E + 255) / 256, 256, 0, stream>>>(ei, ety, cursor, payload, flags, E);

  dim3 tg(DIM / 32, DIM / 32, NREL), tb(32, 8);
  int gemm_blocks = 8 * (32 * 9);   // 2304: 256 m-tiles x 9 (r,bn)

  // ---- layer 1 (H=4, ELU) ----
  transpose_w<<<tg, tb, 0, stream>>>(W1, Wt, flags);
  hipMemsetAsync(Wqkb, 0, (size_t)DIM * 32 * 2, stream);
  wqk_kernel<4><<<(NREL * DIM) / 4, 256, 0, stream>>>(W1, q1, k1, Wqkb, flags);
  pack_b<<<12, 256, 0, stream>>>(Wqkb, Bpk);
  qnkn_mfma<<<nN / 64, 256, 0, stream>>>(xb, Bpk, qn, kn, nN);
  gemm_bf16<<<gemm_blocks, 512, 0, stream>>>(xb, Wt, xr, nN);
  agg_kernel<4, true, false><<<nN / 4, 256, 0, stream>>>(xr, qn, kn, offs, payload, b1, h,
                                                         flags, nN, E);

  // ---- layer 2 (H=1, no activation) ----
  transpose_w<<<tg, tb, 0, stream>>>(W2, Wt, flags);
  hipMemsetAsync(Wqkb, 0, (size_t)DIM * 32 * 2, stream);
  wqk_kernel<1><<<(NREL * DIM) / 4, 256, 0, stream>>>(W2, q2, k2, Wqkb, flags);
  pack_b<<<12, 256, 0, stream>>>(Wqkb, Bpk);
  qnkn_mfma<<<nN / 64, 256, 0, stream>>>(h, Bpk, qn, kn, nN);
  gemm_bf16<<<gemm_blocks, 512, 0, stream>>>(h, Wt, xr, nN);
  agg_kernel<1, false, true><<<nN / 4, 256, 0, stream>>>(xr, qn, kn, offs, payload, b2,
                                                         d_out, flags, nN, E);
}